// Round 13
// baseline (61.077 us; speedup 1.0000x reference)
//
#include <hip/hip_runtime.h>

// DeepSeek-MLA sparse attention, absorbed formulation, full bf16-MFMA pipeline.
// B=2 NQ=1024 NKV=2048 K=64 D=1024 H=16 LAT=128 HD=64
// Round-13 = round-12 resubmitted (bench died on UnresponsiveContainer infra
// error, no kernel signal). x_kv conversion folded into K2 via T14-ordered
// fp32 reg-staging (issue loads -> compute -> vmcnt(0) -> cvt+ds_write).
// Saves the 24 MB x_kv roundtrip in megaconv (50->34 MB). LDS image +
// accumulation order bit-identical -> absmax canary stays exactly 0.0078125.
#define NKVc  2048
#define SCALE 0.125f

typedef unsigned short u16;
typedef __attribute__((ext_vector_type(8))) short short8b;     // 8 bf16 (MFMA frag)
typedef __attribute__((ext_vector_type(8))) unsigned short ushort8;
typedef __attribute__((ext_vector_type(4))) float f32x4;

__device__ __forceinline__ u16 f2bf(float f) {
  unsigned int u = __float_as_uint(f);
  return (u16)((u + 0x7FFFu + ((u >> 16) & 1u)) >> 16);   // RNE
}

#define GLOAD16(gp, lp) \
  __builtin_amdgcn_global_load_lds( \
      (const __attribute__((address_space(1))) unsigned int*)(gp), \
      (__attribute__((address_space(3))) unsigned int*)(lp), 16, 0, 0)

// ---------------------------------------------------------------------------
// Mega-conversion (x_kv removed -- now converted inline in K2). Unit = 8 elem.
// Segments: xq[0,262144) wq[..393216) wkvd[..409600) wv[..425984)
//           wout[..557056) wkt[..573440). grid = 2240.
// ---------------------------------------------------------------------------
__device__ __forceinline__ void conv8(const float* __restrict__ in,
                                      u16* __restrict__ out, int j) {
  float4 f0 = ((const float4*)in)[j * 2];
  float4 f1 = ((const float4*)in)[j * 2 + 1];
  ushort4 a, b;
  a.x = f2bf(f0.x); a.y = f2bf(f0.y); a.z = f2bf(f0.z); a.w = f2bf(f0.w);
  b.x = f2bf(f1.x); b.y = f2bf(f1.y); b.z = f2bf(f1.z); b.w = f2bf(f1.w);
  ((ushort4*)out)[j * 2] = a;
  ((ushort4*)out)[j * 2 + 1] = b;
}

__global__ __launch_bounds__(256)
void megaconv(const float* __restrict__ xq, const float* __restrict__ wq,
              const float* __restrict__ wkvd, const float* __restrict__ wkvu,
              const float* __restrict__ wout,
              u16* __restrict__ xq_bf, u16* __restrict__ wq_bf,
              u16* __restrict__ wkvd_bf, u16* __restrict__ wv_bf,
              u16* __restrict__ wout_bf, u16* __restrict__ wkt) {
  int i = blockIdx.x * 256 + threadIdx.x;
  if (i < 262144) { conv8(xq, xq_bf, i); return; }
  if (i < 393216) { conv8(wq, wq_bf, i - 262144); return; }
  if (i < 409600) { conv8(wkvd, wkvd_bf, i - 393216); return; }
  if (i < 425984) { conv8(wkvu + 131072, wv_bf, i - 409600); return; }
  if (i < 557056) { conv8(wout, wout_bf, i - 425984); return; }
  {
    int o = (i - 557056) * 8;           // 8 consecutive hd in one (h,l)
    int hd0 = o & 63;
    int l = (o >> 6) & 127;
    int h = o >> 13;
    const float* src = wkvu + (h * 64 + hd0) * 128 + l;
    ushort8 v;
#pragma unroll
    for (int j = 0; j < 8; ++j) v[j] = f2bf(src[j * 128]);
    *(ushort8*)&wkt[o] = v;
  }
}

// ---------------------------------------------------------------------------
// GEMM-NT core (BM=64, BN=64, BK=NSUB*32, 4 waves 2x2), caller-owned LDS.
// 2-phase double buffer, full drain per step (proven structure).
// ---------------------------------------------------------------------------
template<int NSUB>
__device__ __forceinline__ void gemm_loop(
    u16* As, u16* Bs, int bm, int bn,
    const u16* __restrict__ A, int lda,
    const u16* __restrict__ B, int ldb, int K, f32x4 (&acc)[2][2]) {
  const int tid = threadIdx.x;
  const int w = tid >> 6, lane = tid & 63;
  const int wr = w >> 1, wc = w & 1;
  constexpr int BUF = NSUB * 256 * 8;

  auto stage = [&](int buf, int t) {
#pragma unroll
    for (int sub = 0; sub < NSUB; ++sub) {
      int s = w * 64 + lane;
      int row = s >> 2;
      int kc = (s & 3) ^ ((row >> 1) & 3);
      int kg = t * (NSUB * 32) + sub * 32 + kc * 8;
      GLOAD16(A + (size_t)(bm + row) * lda + kg,
              As + buf * BUF + (sub * 256 + w * 64) * 8);
      GLOAD16(B + (size_t)(bn + row) * ldb + kg,
              Bs + buf * BUF + (sub * 256 + w * 64) * 8);
    }
  };

  auto compute = [&](int buf) {
#pragma unroll
    for (int sub = 0; sub < NSUB; ++sub) {
      short8b a[2], b[2];
#pragma unroll
      for (int m = 0; m < 2; ++m) {
        int row = wr * 32 + m * 16 + (lane & 15);
        int slot = sub * 256 + row * 4 + ((lane >> 4) ^ ((row >> 1) & 3));
        a[m] = *(const short8b*)&As[buf * BUF + slot * 8];
      }
#pragma unroll
      for (int n = 0; n < 2; ++n) {
        int col = wc * 32 + n * 16 + (lane & 15);
        int slot = sub * 256 + col * 4 + ((lane >> 4) ^ ((col >> 1) & 3));
        b[n] = *(const short8b*)&Bs[buf * BUF + slot * 8];
      }
#pragma unroll
      for (int m = 0; m < 2; ++m)
#pragma unroll
        for (int n = 0; n < 2; ++n)
          acc[m][n] = __builtin_amdgcn_mfma_f32_16x16x32_bf16(a[m], b[n], acc[m][n], 0, 0, 0);
    }
  };

  stage(0, 0);
  asm volatile("s_waitcnt vmcnt(0)" ::: "memory");
  __syncthreads();
  const int nk = K / (NSUB * 32);
  for (int t = 0; t < nk; ++t) {
    int cur = t & 1;
    if (t + 1 < nk) stage(cur ^ 1, t + 1);
    compute(cur);
    asm volatile("s_waitcnt vmcnt(0)" ::: "memory");
    __syncthreads();
  }
}

// ---------------------------------------------------------------------------
// K2 variant: A operand is fp32, converted in-register (T14 order: issue ->
// compute -> vmcnt(0) -> cvt+ds_write). Produces the bit-identical LDS image
// the gload_lds path produced (slot sub*256+s holds row=s>>2, chunk kc).
// B operand stays bf16 gload_lds. NSUB=2.
// ---------------------------------------------------------------------------
__device__ __forceinline__ void gemm_loop_f32A(
    u16* As, u16* Bs, int bm, int bn,
    const float* __restrict__ Af, int lda,
    const u16* __restrict__ B, int ldb, int K, f32x4 (&acc)[2][2]) {
  const int tid = threadIdx.x;
  const int w = tid >> 6, lane = tid & 63;
  const int wr = w >> 1, wc = w & 1;
  constexpr int BUF = 2 * 256 * 8;
  const int s = w * 64 + lane;
  const int row = s >> 2;
  const int kc = (s & 3) ^ ((row >> 1) & 3);

  float4 fa[2][2];

  auto issueA = [&](int t) {
#pragma unroll
    for (int sub = 0; sub < 2; ++sub) {
      const float* g = Af + (size_t)(bm + row) * lda + (t * 64 + sub * 32 + kc * 8);
      fa[sub][0] = *(const float4*)g;
      fa[sub][1] = *(const float4*)(g + 4);
    }
  };
  auto issueB = [&](int buf, int t) {
#pragma unroll
    for (int sub = 0; sub < 2; ++sub) {
      int kg = t * 64 + sub * 32 + kc * 8;
      GLOAD16(B + (size_t)(bn + row) * ldb + kg,
              Bs + buf * BUF + (sub * 256 + w * 64) * 8);
    }
  };
  auto writeA = [&](int buf) {
#pragma unroll
    for (int sub = 0; sub < 2; ++sub) {
      ushort8 v;
      v[0] = f2bf(fa[sub][0].x); v[1] = f2bf(fa[sub][0].y);
      v[2] = f2bf(fa[sub][0].z); v[3] = f2bf(fa[sub][0].w);
      v[4] = f2bf(fa[sub][1].x); v[5] = f2bf(fa[sub][1].y);
      v[6] = f2bf(fa[sub][1].z); v[7] = f2bf(fa[sub][1].w);
      *(ushort8*)&As[buf * BUF + (sub * 256 + s) * 8] = v;
    }
  };
  auto compute = [&](int buf) {
#pragma unroll
    for (int sub = 0; sub < 2; ++sub) {
      short8b a[2], b[2];
#pragma unroll
      for (int m = 0; m < 2; ++m) {
        int r2 = wr * 32 + m * 16 + (lane & 15);
        int slot = sub * 256 + r2 * 4 + ((lane >> 4) ^ ((r2 >> 1) & 3));
        a[m] = *(const short8b*)&As[buf * BUF + slot * 8];
      }
#pragma unroll
      for (int n = 0; n < 2; ++n) {
        int col = wc * 32 + n * 16 + (lane & 15);
        int slot = sub * 256 + col * 4 + ((lane >> 4) ^ ((col >> 1) & 3));
        b[n] = *(const short8b*)&Bs[buf * BUF + slot * 8];
      }
#pragma unroll
      for (int m = 0; m < 2; ++m)
#pragma unroll
        for (int n = 0; n < 2; ++n)
          acc[m][n] = __builtin_amdgcn_mfma_f32_16x16x32_bf16(a[m], b[n], acc[m][n], 0, 0, 0);
    }
  };

  issueA(0); issueB(0, 0);
  asm volatile("s_waitcnt vmcnt(0)" ::: "memory");
  writeA(0);
  __syncthreads();
  const int nk = K >> 6;
  for (int t = 0; t < nk; ++t) {
    int cur = t & 1;
    if (t + 1 < nk) { issueA(t + 1); issueB(cur ^ 1, t + 1); }
    compute(cur);
    asm volatile("s_waitcnt vmcnt(0)" ::: "memory");
    if (t + 1 < nk) writeA(cur ^ 1);   // As[cur^1] last read at compute(t-1)
    __syncthreads();
  }
}

__device__ __forceinline__ void gemm_epi(
    f32x4 (&acc)[2][2], int bm, int bn,
    float* __restrict__ C, u16* __restrict__ Cb, int ldc, bool obf) {
  const int lane = threadIdx.x & 63;
  const int w = threadIdx.x >> 6;
  const int wr = w >> 1, wc = w & 1;
#pragma unroll
  for (int m = 0; m < 2; ++m) {
    int row0 = bm + wr * 32 + m * 16 + (lane >> 4) * 4;
#pragma unroll
    for (int n = 0; n < 2; ++n) {
      int col = bn + wc * 32 + n * 16 + (lane & 15);
      if (obf) {
#pragma unroll
        for (int r = 0; r < 4; ++r)
          Cb[(size_t)(row0 + r) * ldc + col] = f2bf(acc[m][n][r]);
      } else {
#pragma unroll
        for (int r = 0; r < 4; ++r)
          C[(size_t)(row0 + r) * ldc + col] = acc[m][n][r];
      }
    }
  }
}

// standalone wrapper, BK=128 (K5, K6)
__global__ __launch_bounds__(256)
void gemm_nt_g4(const u16* __restrict__ A, int lda, long sAz,
                const u16* __restrict__ B, int ldb, long sBz,
                float* __restrict__ C, u16* __restrict__ Cb,
                int ldc, long sCz, int K, int obf) {
  __shared__ __align__(16) u16 As[2 * 1024 * 8];
  __shared__ __align__(16) u16 Bs[2 * 1024 * 8];
  f32x4 acc[2][2] = {};
  gemm_loop<4>(As, Bs, blockIdx.y * 64, blockIdx.x * 64,
               A + (size_t)blockIdx.z * sAz, lda,
               B + (size_t)blockIdx.z * sBz, ldb, K, acc);
  gemm_epi(acc, blockIdx.y * 64, blockIdx.x * 64,
           C ? C + (size_t)blockIdx.z * sCz : nullptr,
           Cb ? Cb + (size_t)blockIdx.z * sCz : nullptr, ldc, obf != 0);
}

// ---------------------------------------------------------------------------
// D1: [0,512)   K1+K3 fused: q-subblock in regs -> qlat[*, h=bx, :] directly
//     [512,640) K2: c_kvb = bf16(x_kv_f32 @ W_kvd^T), inline A-conversion
// One shared 32 KB LDS allocation for both paths.
// ---------------------------------------------------------------------------
__global__ __launch_bounds__(256)
void d1_fused(const u16* __restrict__ xq_bf, const u16* __restrict__ wq_bf,
              const float* __restrict__ xkv, const u16* __restrict__ wkvd_bf,
              const u16* __restrict__ wkt, u16* __restrict__ qlat_bf,
              u16* __restrict__ c_kvb) {
  __shared__ __align__(16) u16 As[2 * 512 * 8];   // 16 KB
  __shared__ __align__(16) u16 Bs[2 * 512 * 8];   // 16 KB
  const int b = blockIdx.x;
  const int tid = threadIdx.x;
  const int w = tid >> 6, lane = tid & 63;
  const int wr = w >> 1, wc = w & 1;
  f32x4 acc[2][2] = {};

  if (b >= 512) {   // K2 path: fp32 A inline-converted
    int b2 = b - 512;
    int bm = (b2 >> 1) * 64, bn = (b2 & 1) * 64;
    gemm_loop_f32A(As, Bs, bm, bn, xkv, 1024, wkvd_bf, 1024, 1024, acc);
    gemm_epi(acc, bm, bn, nullptr, c_kvb, 128, true);
    return;
  }

  // --- K1 phase: q_sub = x_q[by-rows] @ W_q[h-rows]^T (64x64, head h=bx) ---
  const int h = b & 15, bm = (b >> 4) * 64;
  gemm_loop<2>(As, Bs, bm, h * 64, xq_bf, 1024, wq_bf, 1024, 1024, acc);
  // loop ended with full drain + barrier -> As/Bs free for reuse.

  // --- K3 phase: qlat[bm-rows][h][l] = q_sub @ wkt[h]^T  (M=64,N=128,K=64) --
#pragma unroll
  for (int i = 0; i < 4; ++i) {
    int s = (w * 4 + i) * 64 + lane;      // 0..1023
    int l = s >> 3, c = s & 7;
    GLOAD16(wkt + h * 8192 + l * 64 + ((c ^ (l & 7)) * 8), Bs + s * 8);
  }
#pragma unroll
  for (int mm = 0; mm < 2; ++mm)
#pragma unroll
    for (int nn = 0; nn < 2; ++nn) {
      int hd = wc * 32 + nn * 16 + (lane & 15);
      int c = hd >> 3;
#pragma unroll
      for (int rr = 0; rr < 4; ++rr) {
        int row = wr * 32 + mm * 16 + (lane >> 4) * 4 + rr;
        As[row * 64 + ((c ^ (row & 7)) * 8) + (hd & 7)] = f2bf(acc[mm][nn][rr]);
      }
    }
  asm volatile("s_waitcnt vmcnt(0)" ::: "memory");
  __syncthreads();

  f32x4 acc2[2][4] = {};
#pragma unroll
  for (int ks = 0; ks < 2; ++ks) {
    short8b af[2], bv[4];
#pragma unroll
    for (int mm = 0; mm < 2; ++mm) {
      int row = wr * 32 + mm * 16 + (lane & 15);
      int ch = ks * 4 + (lane >> 4);
      af[mm] = *(const short8b*)&As[row * 64 + ((ch ^ (row & 7)) * 8)];
    }
#pragma unroll
    for (int nf = 0; nf < 4; ++nf) {
      int l = wc * 64 + nf * 16 + (lane & 15);
      int ch = ks * 4 + (lane >> 4);
      bv[nf] = *(const short8b*)&Bs[(l * 8 + (ch ^ (l & 7))) * 8];
    }
#pragma unroll
    for (int mm = 0; mm < 2; ++mm)
#pragma unroll
      for (int nf = 0; nf < 4; ++nf)
        acc2[mm][nf] = __builtin_amdgcn_mfma_f32_16x16x32_bf16(af[mm], bv[nf], acc2[mm][nf], 0, 0, 0);
  }
#pragma unroll
  for (int mm = 0; mm < 2; ++mm) {
    int row0 = bm + wr * 32 + mm * 16 + (lane >> 4) * 4;
#pragma unroll
    for (int nf = 0; nf < 4; ++nf) {
      int l = wc * 64 + nf * 16 + (lane & 15);
#pragma unroll
      for (int r = 0; r < 4; ++r)
        qlat_bf[(size_t)(row0 + r) * 2048 + h * 128 + l] = f2bf(acc2[mm][nf][r]);
    }
  }
}

// ---------------------------------------------------------------------------
// Fused sparse attention in latent space, bf16 MFMA. One block per (b,q).
// (unchanged -- proven correct)
// ---------------------------------------------------------------------------
__global__ __launch_bounds__(256)
void attn_mfma(const u16* __restrict__ c_kvb,   // (B, 2048, 128) bf16
               const u16* __restrict__ q_latb,  // (BQ, 16, 128) bf16
               const int* __restrict__ indices, // (BQ, 64)
               u16* __restrict__ cw_bf) {       // (BQ, 16, 128) bf16
  __shared__ __align__(16) u16 qls[256 * 8];
  __shared__ __align__(16) u16 csa[1024 * 8];
  __shared__ __align__(16) u16 cst[128 * 72];
  __shared__ __align__(16) u16 pT[16 * 72];
  __shared__ __align__(16) float redmax[64];
  __shared__ __align__(16) float redsum[64];
  __shared__ __align__(16) u16 outst[2048];

  const int tid = threadIdx.x;
  const int w = tid >> 6, lane = tid & 63;
  const int bq = blockIdx.x;
  const int b = bq >> 10;

  {
    int h = tid >> 4, c = tid & 15;
    ushort8 v = *(const ushort8*)(q_latb + (size_t)bq * 2048 + tid * 8);
    *(ushort8*)&qls[(h * 16 + (c ^ h)) * 8] = v;
  }
  {
    int kidx = indices[bq * 64 + lane];
    const u16* src = c_kvb + ((size_t)b * NKVc + kidx) * 128 + w * 32;
    ushort8 v[4];
#pragma unroll
    for (int t = 0; t < 4; ++t) v[t] = *(const ushort8*)(src + t * 8);
#pragma unroll
    for (int t = 0; t < 4; ++t) {
      int c = w * 4 + t;
      *(ushort8*)&csa[(lane * 16 + (c ^ (lane & 15))) * 8] = v[t];
    }
#pragma unroll
    for (int t = 0; t < 4; ++t)
#pragma unroll
      for (int j = 0; j < 8; ++j)
        cst[(w * 32 + t * 8 + j) * 72 + lane] = v[t][j];
  }
  __syncthreads();

  f32x4 sacc = {};
#pragma unroll
  for (int kc = 0; kc < 4; ++kc) {
    int ar = w * 16 + (lane & 15);
    int ac = kc * 4 + (lane >> 4);
    short8b av = *(const short8b*)&csa[(ar * 16 + (ac ^ (ar & 15))) * 8];
    int bh = lane & 15;
    short8b bv = *(const short8b*)&qls[(bh * 16 + (ac ^ bh)) * 8];
    sacc = __builtin_amdgcn_mfma_f32_16x16x32_bf16(av, bv, sacc, 0, 0, 0);
  }
  float s0 = sacc[0] * SCALE, s1 = sacc[1] * SCALE;
  float s2 = sacc[2] * SCALE, s3 = sacc[3] * SCALE;
  float mx = fmaxf(fmaxf(s0, s1), fmaxf(s2, s3));
  mx = fmaxf(mx, __shfl_xor(mx, 16));
  mx = fmaxf(mx, __shfl_xor(mx, 32));
  if (lane < 16) redmax[w * 16 + lane] = mx;
  __syncthreads();
  const int h = lane & 15;
  float m4 = fmaxf(fmaxf(redmax[h], redmax[16 + h]),
                   fmaxf(redmax[32 + h], redmax[48 + h]));
  float p0 = __expf(s0 - m4), p1 = __expf(s1 - m4);
  float p2 = __expf(s2 - m4), p3 = __expf(s3 - m4);
  float sm = p0 + p1 + p2 + p3;
  sm += __shfl_xor(sm, 16);
  sm += __shfl_xor(sm, 32);
  if (lane < 16) redsum[w * 16 + lane] = sm;
  __syncthreads();
  float tot = redsum[h] + redsum[16 + h] + redsum[32 + h] + redsum[48 + h];
  float inv = 1.0f / tot;
  {
    ushort4 pw;
    pw.x = f2bf(p0 * inv); pw.y = f2bf(p1 * inv);
    pw.z = f2bf(p2 * inv); pw.w = f2bf(p3 * inv);
    *(ushort4*)&pT[h * 72 + w * 16 + (lane >> 4) * 4] = pw;
  }
  __syncthreads();

  f32x4 pacc0 = {}, pacc1 = {};
#pragma unroll
  for (int kc = 0; kc < 2; ++kc) {
    short8b pa = *(const short8b*)&pT[(lane & 15) * 72 + kc * 32 + (lane >> 4) * 8];
    int cch = kc * 4 + (lane >> 4);
    int n0 = w * 32 + (lane & 15);
    short8b b0 = *(const short8b*)&cst[n0 * 72 + cch * 8];
    short8b b1 = *(const short8b*)&cst[(n0 + 16) * 72 + cch * 8];
    pacc0 = __builtin_amdgcn_mfma_f32_16x16x32_bf16(pa, b0, pacc0, 0, 0, 0);
    pacc1 = __builtin_amdgcn_mfma_f32_16x16x32_bf16(pa, b1, pacc1, 0, 0, 0);
  }
#pragma unroll
  for (int r = 0; r < 4; ++r) {
    int hh = (lane >> 4) * 4 + r;
    outst[hh * 128 + w * 32 + (lane & 15)] = f2bf(pacc0[r]);
    outst[hh * 128 + w * 32 + 16 + (lane & 15)] = f2bf(pacc1[r]);
  }
  __syncthreads();
  *(ushort8*)(cw_bf + (size_t)bq * 2048 + tid * 8) = *(const ushort8*)&outst[tid * 8];
}

extern "C" void kernel_launch(void* const* d_in, const int* in_sizes, int n_in,
                              void* d_out, int out_size, void* d_ws, size_t ws_size,
                              hipStream_t stream) {
  const float* x_q    = (const float*)d_in[0];
  const float* x_kv   = (const float*)d_in[1];
  const int*   idx    = (const int*)  d_in[2];
  const float* W_q    = (const float*)d_in[3];
  const float* W_kvd  = (const float*)d_in[4];
  const float* W_kvu  = (const float*)d_in[5];
  const float* W_out  = (const float*)d_in[6];
  float* out = (float*)d_out;

  // byte-offset workspace carve; top = 42 MB (proven). xkv_bf eliminated.
  char* wsb = (char*)d_ws;
  u16* xq_bf   = (u16*)(wsb + 0);                            // 4 MB
  u16* wq_bf   = (u16*)(wsb + (4u << 20));                   // 2 MB
  u16* wkvd_bf = (u16*)(wsb + (14u << 20));                  // 256 KB
  u16* wkt     = (u16*)(wsb + (14u << 20) + (256u << 10));   // 256 KB
  u16* wv_bf   = (u16*)(wsb + (14u << 20) + (512u << 10));   // 256 KB
  u16* wout_bf = (u16*)(wsb + (14u << 20) + (768u << 10));   // 2 MB
  u16* c_kvb   = (u16*)(wsb + (21u << 20));                  // 1 MB
  u16* qlat_bf = (u16*)(wsb + (22u << 20));                  // 8 MB
  u16* cw_bf   = (u16*)(wsb + (30u << 20));                  // 8 MB
  u16* o_bf    = (u16*)(wsb + (38u << 20));                  // 4 MB

  // C0: conversions (x_kv no longer here)
  megaconv<<<dim3(2240), 256, 0, stream>>>(x_q, W_q, W_kvd, W_kvu, W_out,
                                           xq_bf, wq_bf, wkvd_bf, wv_bf,
                                           wout_bf, wkt);

  // D1: K1+K3 fused (512 blocks) || K2 inline-conv (128 blocks)
  d1_fused<<<dim3(640), 256, 0, stream>>>(xq_bf, wq_bf, x_kv, wkvd_bf,
                                          wkt, qlat_bf, c_kvb);

  // K4: fused gather + latent scores + softmax + latent PV (bf16 MFMA)
  attn_mfma<<<dim3(2048), 256, 0, stream>>>(c_kvb, qlat_bf, idx, cw_bf);

  // K5: o_bf[bq,h*64+n] = bf16(cw[bq,h,:] @ W_v[h]^T)  (BK=128, nk=1)
  gemm_nt_g4<<<dim3(1, 32, 16), 256, 0, stream>>>(
      cw_bf, 2048, 128, wv_bf, 128, 8192, nullptr, o_bf, 1024, 64, 128, 1);

  // K6: out = o @ W_out^T  (fp32 out, BK=128, nk=8)
  gemm_nt_g4<<<dim3(16, 32, 1), 256, 0, stream>>>(
      o_bf, 1024, 0, wout_bf, 1024, 0, out, nullptr, 1024, 0, 1024, 0);
}

// Round 14
// 60.400 us; speedup vs baseline: 1.0112x; 1.0112x over previous
//
#include <hip/hip_runtime.h>

// DeepSeek-MLA sparse attention, absorbed formulation, full bf16-MFMA pipeline.
// B=2 NQ=1024 NKV=2048 K=64 D=1024 H=16 LAT=128 HD=64
// Round-14: REVERT round-12/13's K2 inline-fp32 staging (regressed 59.2->61.1;
// T14 reg-staging cost > megaconv traffic saving -- matches catalog's
// "reg-staging ~16% worse than gload_lds where gload_lds applies"). Back to
// round-11's proven megaconv+bf16-K2. NEW (one lever): attn processes 2
// queries per block serially (grid 2048->1024, same LDS/occupancy, same math
// order per query -> absmax canary exactly 0.0078125).
#define NKVc  2048
#define SCALE 0.125f

typedef unsigned short u16;
typedef __attribute__((ext_vector_type(8))) short short8b;     // 8 bf16 (MFMA frag)
typedef __attribute__((ext_vector_type(8))) unsigned short ushort8;
typedef __attribute__((ext_vector_type(4))) float f32x4;

__device__ __forceinline__ u16 f2bf(float f) {
  unsigned int u = __float_as_uint(f);
  return (u16)((u + 0x7FFFu + ((u >> 16) & 1u)) >> 16);   // RNE
}

#define GLOAD16(gp, lp) \
  __builtin_amdgcn_global_load_lds( \
      (const __attribute__((address_space(1))) unsigned int*)(gp), \
      (__attribute__((address_space(3))) unsigned int*)(lp), 16, 0, 0)

// ---------------------------------------------------------------------------
// Mega-conversion: all fp32->bf16 prep in ONE dispatch. Unit = 8 elements.
// ---------------------------------------------------------------------------
__device__ __forceinline__ void conv8(const float* __restrict__ in,
                                      u16* __restrict__ out, int j) {
  float4 f0 = ((const float4*)in)[j * 2];
  float4 f1 = ((const float4*)in)[j * 2 + 1];
  ushort4 a, b;
  a.x = f2bf(f0.x); a.y = f2bf(f0.y); a.z = f2bf(f0.z); a.w = f2bf(f0.w);
  b.x = f2bf(f1.x); b.y = f2bf(f1.y); b.z = f2bf(f1.z); b.w = f2bf(f1.w);
  ((ushort4*)out)[j * 2] = a;
  ((ushort4*)out)[j * 2 + 1] = b;
}

__global__ __launch_bounds__(256)
void megaconv(const float* __restrict__ xq, const float* __restrict__ wq,
              const float* __restrict__ xkv, const float* __restrict__ wkvd,
              const float* __restrict__ wkvu, const float* __restrict__ wout,
              u16* __restrict__ xq_bf, u16* __restrict__ wq_bf,
              u16* __restrict__ xkv_bf, u16* __restrict__ wkvd_bf,
              u16* __restrict__ wv_bf, u16* __restrict__ wout_bf,
              u16* __restrict__ wkt) {
  int i = blockIdx.x * 256 + threadIdx.x;
  if (i < 262144) { conv8(xq, xq_bf, i); return; }
  if (i < 393216) { conv8(wq, wq_bf, i - 262144); return; }
  if (i < 917504) { conv8(xkv, xkv_bf, i - 393216); return; }
  if (i < 933888) { conv8(wkvd, wkvd_bf, i - 917504); return; }
  if (i < 950272) { conv8(wkvu + 131072, wv_bf, i - 933888); return; }
  if (i < 1081344) { conv8(wout, wout_bf, i - 950272); return; }
  {
    int o = (i - 1081344) * 8;          // 8 consecutive hd in one (h,l)
    int hd0 = o & 63;
    int l = (o >> 6) & 127;
    int h = o >> 13;
    const float* src = wkvu + (h * 64 + hd0) * 128 + l;
    ushort8 v;
#pragma unroll
    for (int j = 0; j < 8; ++j) v[j] = f2bf(src[j * 128]);
    *(ushort8*)&wkt[o] = v;
  }
}

// ---------------------------------------------------------------------------
// GEMM-NT core (BM=64, BN=64, BK=NSUB*32, 4 waves 2x2), caller-owned LDS.
// 2-phase double buffer, full drain per step (proven structure).
// ---------------------------------------------------------------------------
template<int NSUB>
__device__ __forceinline__ void gemm_loop(
    u16* As, u16* Bs, int bm, int bn,
    const u16* __restrict__ A, int lda,
    const u16* __restrict__ B, int ldb, int K, f32x4 (&acc)[2][2]) {
  const int tid = threadIdx.x;
  const int w = tid >> 6, lane = tid & 63;
  const int wr = w >> 1, wc = w & 1;
  constexpr int BUF = NSUB * 256 * 8;

  auto stage = [&](int buf, int t) {
#pragma unroll
    for (int sub = 0; sub < NSUB; ++sub) {
      int s = w * 64 + lane;
      int row = s >> 2;
      int kc = (s & 3) ^ ((row >> 1) & 3);
      int kg = t * (NSUB * 32) + sub * 32 + kc * 8;
      GLOAD16(A + (size_t)(bm + row) * lda + kg,
              As + buf * BUF + (sub * 256 + w * 64) * 8);
      GLOAD16(B + (size_t)(bn + row) * ldb + kg,
              Bs + buf * BUF + (sub * 256 + w * 64) * 8);
    }
  };

  auto compute = [&](int buf) {
#pragma unroll
    for (int sub = 0; sub < NSUB; ++sub) {
      short8b a[2], b[2];
#pragma unroll
      for (int m = 0; m < 2; ++m) {
        int row = wr * 32 + m * 16 + (lane & 15);
        int slot = sub * 256 + row * 4 + ((lane >> 4) ^ ((row >> 1) & 3));
        a[m] = *(const short8b*)&As[buf * BUF + slot * 8];
      }
#pragma unroll
      for (int n = 0; n < 2; ++n) {
        int col = wc * 32 + n * 16 + (lane & 15);
        int slot = sub * 256 + col * 4 + ((lane >> 4) ^ ((col >> 1) & 3));
        b[n] = *(const short8b*)&Bs[buf * BUF + slot * 8];
      }
#pragma unroll
      for (int m = 0; m < 2; ++m)
#pragma unroll
        for (int n = 0; n < 2; ++n)
          acc[m][n] = __builtin_amdgcn_mfma_f32_16x16x32_bf16(a[m], b[n], acc[m][n], 0, 0, 0);
    }
  };

  stage(0, 0);
  asm volatile("s_waitcnt vmcnt(0)" ::: "memory");
  __syncthreads();
  const int nk = K / (NSUB * 32);
  for (int t = 0; t < nk; ++t) {
    int cur = t & 1;
    if (t + 1 < nk) stage(cur ^ 1, t + 1);
    compute(cur);
    asm volatile("s_waitcnt vmcnt(0)" ::: "memory");
    __syncthreads();
  }
}

__device__ __forceinline__ void gemm_epi(
    f32x4 (&acc)[2][2], int bm, int bn,
    float* __restrict__ C, u16* __restrict__ Cb, int ldc, bool obf) {
  const int lane = threadIdx.x & 63;
  const int w = threadIdx.x >> 6;
  const int wr = w >> 1, wc = w & 1;
#pragma unroll
  for (int m = 0; m < 2; ++m) {
    int row0 = bm + wr * 32 + m * 16 + (lane >> 4) * 4;
#pragma unroll
    for (int n = 0; n < 2; ++n) {
      int col = bn + wc * 32 + n * 16 + (lane & 15);
      if (obf) {
#pragma unroll
        for (int r = 0; r < 4; ++r)
          Cb[(size_t)(row0 + r) * ldc + col] = f2bf(acc[m][n][r]);
      } else {
#pragma unroll
        for (int r = 0; r < 4; ++r)
          C[(size_t)(row0 + r) * ldc + col] = acc[m][n][r];
      }
    }
  }
}

// standalone wrapper, BK=128 (K5, K6)
__global__ __launch_bounds__(256)
void gemm_nt_g4(const u16* __restrict__ A, int lda, long sAz,
                const u16* __restrict__ B, int ldb, long sBz,
                float* __restrict__ C, u16* __restrict__ Cb,
                int ldc, long sCz, int K, int obf) {
  __shared__ __align__(16) u16 As[2 * 1024 * 8];
  __shared__ __align__(16) u16 Bs[2 * 1024 * 8];
  f32x4 acc[2][2] = {};
  gemm_loop<4>(As, Bs, blockIdx.y * 64, blockIdx.x * 64,
               A + (size_t)blockIdx.z * sAz, lda,
               B + (size_t)blockIdx.z * sBz, ldb, K, acc);
  gemm_epi(acc, blockIdx.y * 64, blockIdx.x * 64,
           C ? C + (size_t)blockIdx.z * sCz : nullptr,
           Cb ? Cb + (size_t)blockIdx.z * sCz : nullptr, ldc, obf != 0);
}

// ---------------------------------------------------------------------------
// D1: [0,512)   K1+K3 fused: q-subblock in regs -> qlat[*, h=bx, :] directly
//     [512,640) K2: c_kvb = bf16(x_kv @ W_kvd^T), K=1024 (bf16 gload path)
// One shared 32 KB LDS allocation for both paths.
// ---------------------------------------------------------------------------
__global__ __launch_bounds__(256)
void d1_fused(const u16* __restrict__ xq_bf, const u16* __restrict__ wq_bf,
              const u16* __restrict__ xkv_bf, const u16* __restrict__ wkvd_bf,
              const u16* __restrict__ wkt, u16* __restrict__ qlat_bf,
              u16* __restrict__ c_kvb) {
  __shared__ __align__(16) u16 As[2 * 512 * 8];   // 16 KB
  __shared__ __align__(16) u16 Bs[2 * 512 * 8];   // 16 KB
  const int b = blockIdx.x;
  const int tid = threadIdx.x;
  const int w = tid >> 6, lane = tid & 63;
  const int wr = w >> 1, wc = w & 1;
  f32x4 acc[2][2] = {};

  if (b >= 512) {   // K2 path
    int b2 = b - 512;
    int bm = (b2 >> 1) * 64, bn = (b2 & 1) * 64;
    gemm_loop<2>(As, Bs, bm, bn, xkv_bf, 1024, wkvd_bf, 1024, 1024, acc);
    gemm_epi(acc, bm, bn, nullptr, c_kvb, 128, true);
    return;
  }

  // --- K1 phase: q_sub = x_q[by-rows] @ W_q[h-rows]^T (64x64, head h=bx) ---
  const int h = b & 15, bm = (b >> 4) * 64;
  gemm_loop<2>(As, Bs, bm, h * 64, xq_bf, 1024, wq_bf, 1024, 1024, acc);
  // loop ended with full drain + barrier -> As/Bs free for reuse.

  // --- K3 phase: qlat[bm-rows][h][l] = q_sub @ wkt[h]^T  (M=64,N=128,K=64) --
#pragma unroll
  for (int i = 0; i < 4; ++i) {
    int s = (w * 4 + i) * 64 + lane;      // 0..1023
    int l = s >> 3, c = s & 7;
    GLOAD16(wkt + h * 8192 + l * 64 + ((c ^ (l & 7)) * 8), Bs + s * 8);
  }
#pragma unroll
  for (int mm = 0; mm < 2; ++mm)
#pragma unroll
    for (int nn = 0; nn < 2; ++nn) {
      int hd = wc * 32 + nn * 16 + (lane & 15);
      int c = hd >> 3;
#pragma unroll
      for (int rr = 0; rr < 4; ++rr) {
        int row = wr * 32 + mm * 16 + (lane >> 4) * 4 + rr;
        As[row * 64 + ((c ^ (row & 7)) * 8) + (hd & 7)] = f2bf(acc[mm][nn][rr]);
      }
    }
  asm volatile("s_waitcnt vmcnt(0)" ::: "memory");
  __syncthreads();

  f32x4 acc2[2][4] = {};
#pragma unroll
  for (int ks = 0; ks < 2; ++ks) {
    short8b af[2], bv[4];
#pragma unroll
    for (int mm = 0; mm < 2; ++mm) {
      int row = wr * 32 + mm * 16 + (lane & 15);
      int ch = ks * 4 + (lane >> 4);
      af[mm] = *(const short8b*)&As[row * 64 + ((ch ^ (row & 7)) * 8)];
    }
#pragma unroll
    for (int nf = 0; nf < 4; ++nf) {
      int l = wc * 64 + nf * 16 + (lane & 15);
      int ch = ks * 4 + (lane >> 4);
      bv[nf] = *(const short8b*)&Bs[(l * 8 + (ch ^ (l & 7))) * 8];
    }
#pragma unroll
    for (int mm = 0; mm < 2; ++mm)
#pragma unroll
      for (int nf = 0; nf < 4; ++nf)
        acc2[mm][nf] = __builtin_amdgcn_mfma_f32_16x16x32_bf16(af[mm], bv[nf], acc2[mm][nf], 0, 0, 0);
  }
#pragma unroll
  for (int mm = 0; mm < 2; ++mm) {
    int row0 = bm + wr * 32 + mm * 16 + (lane >> 4) * 4;
#pragma unroll
    for (int nf = 0; nf < 4; ++nf) {
      int l = wc * 64 + nf * 16 + (lane & 15);
#pragma unroll
      for (int r = 0; r < 4; ++r)
        qlat_bf[(size_t)(row0 + r) * 2048 + h * 128 + l] = f2bf(acc2[mm][nf][r]);
    }
  }
}

// ---------------------------------------------------------------------------
// Fused sparse attention, bf16 MFMA. One block per 2 queries (serial, shared
// LDS). Per-query math identical to the proven 1-query version.
// ---------------------------------------------------------------------------
__global__ __launch_bounds__(256)
void attn_mfma(const u16* __restrict__ c_kvb,   // (B, 2048, 128) bf16
               const u16* __restrict__ q_latb,  // (BQ, 16, 128) bf16
               const int* __restrict__ indices, // (BQ, 64)
               u16* __restrict__ cw_bf) {       // (BQ, 16, 128) bf16
  __shared__ __align__(16) u16 qls[256 * 8];
  __shared__ __align__(16) u16 csa[1024 * 8];
  __shared__ __align__(16) u16 cst[128 * 72];
  __shared__ __align__(16) u16 pT[16 * 72];
  __shared__ __align__(16) float redmax[64];
  __shared__ __align__(16) float redsum[64];
  __shared__ __align__(16) u16 outst[2048];

  const int tid = threadIdx.x;
  const int w = tid >> 6, lane = tid & 63;

  for (int it = 0; it < 2; ++it) {
    const int bq = blockIdx.x * 2 + it;
    const int b = bq >> 10;

    {
      int h = tid >> 4, c = tid & 15;
      ushort8 v = *(const ushort8*)(q_latb + (size_t)bq * 2048 + tid * 8);
      *(ushort8*)&qls[(h * 16 + (c ^ h)) * 8] = v;
    }
    {
      int kidx = indices[bq * 64 + lane];
      const u16* src = c_kvb + ((size_t)b * NKVc + kidx) * 128 + w * 32;
      ushort8 v[4];
#pragma unroll
      for (int t = 0; t < 4; ++t) v[t] = *(const ushort8*)(src + t * 8);
#pragma unroll
      for (int t = 0; t < 4; ++t) {
        int c = w * 4 + t;
        *(ushort8*)&csa[(lane * 16 + (c ^ (lane & 15))) * 8] = v[t];
      }
#pragma unroll
      for (int t = 0; t < 4; ++t)
#pragma unroll
        for (int j = 0; j < 8; ++j)
          cst[(w * 32 + t * 8 + j) * 72 + lane] = v[t][j];
    }
    __syncthreads();

    f32x4 sacc = {};
#pragma unroll
    for (int kc = 0; kc < 4; ++kc) {
      int ar = w * 16 + (lane & 15);
      int ac = kc * 4 + (lane >> 4);
      short8b av = *(const short8b*)&csa[(ar * 16 + (ac ^ (ar & 15))) * 8];
      int bh = lane & 15;
      short8b bv = *(const short8b*)&qls[(bh * 16 + (ac ^ bh)) * 8];
      sacc = __builtin_amdgcn_mfma_f32_16x16x32_bf16(av, bv, sacc, 0, 0, 0);
    }
    float s0 = sacc[0] * SCALE, s1 = sacc[1] * SCALE;
    float s2 = sacc[2] * SCALE, s3 = sacc[3] * SCALE;
    float mx = fmaxf(fmaxf(s0, s1), fmaxf(s2, s3));
    mx = fmaxf(mx, __shfl_xor(mx, 16));
    mx = fmaxf(mx, __shfl_xor(mx, 32));
    if (lane < 16) redmax[w * 16 + lane] = mx;
    __syncthreads();
    const int h = lane & 15;
    float m4 = fmaxf(fmaxf(redmax[h], redmax[16 + h]),
                     fmaxf(redmax[32 + h], redmax[48 + h]));
    float p0 = __expf(s0 - m4), p1 = __expf(s1 - m4);
    float p2 = __expf(s2 - m4), p3 = __expf(s3 - m4);
    float sm = p0 + p1 + p2 + p3;
    sm += __shfl_xor(sm, 16);
    sm += __shfl_xor(sm, 32);
    if (lane < 16) redsum[w * 16 + lane] = sm;
    __syncthreads();
    float tot = redsum[h] + redsum[16 + h] + redsum[32 + h] + redsum[48 + h];
    float inv = 1.0f / tot;
    {
      ushort4 pw;
      pw.x = f2bf(p0 * inv); pw.y = f2bf(p1 * inv);
      pw.z = f2bf(p2 * inv); pw.w = f2bf(p3 * inv);
      *(ushort4*)&pT[h * 72 + w * 16 + (lane >> 4) * 4] = pw;
    }
    __syncthreads();

    f32x4 pacc0 = {}, pacc1 = {};
#pragma unroll
    for (int kc = 0; kc < 2; ++kc) {
      short8b pa = *(const short8b*)&pT[(lane & 15) * 72 + kc * 32 + (lane >> 4) * 8];
      int cch = kc * 4 + (lane >> 4);
      int n0 = w * 32 + (lane & 15);
      short8b b0 = *(const short8b*)&cst[n0 * 72 + cch * 8];
      short8b b1 = *(const short8b*)&cst[(n0 + 16) * 72 + cch * 8];
      pacc0 = __builtin_amdgcn_mfma_f32_16x16x32_bf16(pa, b0, pacc0, 0, 0, 0);
      pacc1 = __builtin_amdgcn_mfma_f32_16x16x32_bf16(pa, b1, pacc1, 0, 0, 0);
    }
#pragma unroll
    for (int r = 0; r < 4; ++r) {
      int hh = (lane >> 4) * 4 + r;
      outst[hh * 128 + w * 32 + (lane & 15)] = f2bf(pacc0[r]);
      outst[hh * 128 + w * 32 + 16 + (lane & 15)] = f2bf(pacc1[r]);
    }
    __syncthreads();
    *(ushort8*)(cw_bf + (size_t)bq * 2048 + tid * 8) = *(const ushort8*)&outst[tid * 8];
    __syncthreads();   // guard LDS reuse by next iteration
  }
}

extern "C" void kernel_launch(void* const* d_in, const int* in_sizes, int n_in,
                              void* d_out, int out_size, void* d_ws, size_t ws_size,
                              hipStream_t stream) {
  const float* x_q    = (const float*)d_in[0];
  const float* x_kv   = (const float*)d_in[1];
  const int*   idx    = (const int*)  d_in[2];
  const float* W_q    = (const float*)d_in[3];
  const float* W_kvd  = (const float*)d_in[4];
  const float* W_kvu  = (const float*)d_in[5];
  const float* W_out  = (const float*)d_in[6];
  float* out = (float*)d_out;

  // byte-offset workspace carve; top = 42 MB (proven footprint)
  char* wsb = (char*)d_ws;
  u16* xq_bf   = (u16*)(wsb + 0);                            // 4 MB
  u16* wq_bf   = (u16*)(wsb + (4u << 20));                   // 2 MB
  u16* xkv_bf  = (u16*)(wsb + (6u << 20));                   // 8 MB
  u16* wkvd_bf = (u16*)(wsb + (14u << 20));                  // 256 KB
  u16* wkt     = (u16*)(wsb + (14u << 20) + (256u << 10));   // 256 KB
  u16* wv_bf   = (u16*)(wsb + (14u << 20) + (512u << 10));   // 256 KB
  u16* wout_bf = (u16*)(wsb + (14u << 20) + (768u << 10));   // 2 MB
  u16* c_kvb   = (u16*)(wsb + (21u << 20));                  // 1 MB
  u16* qlat_bf = (u16*)(wsb + (22u << 20));                  // 8 MB
  u16* cw_bf   = (u16*)(wsb + (30u << 20));                  // 8 MB
  u16* o_bf    = (u16*)(wsb + (38u << 20));                  // 4 MB

  // C0: all conversions in one dispatch
  megaconv<<<dim3(4288), 256, 0, stream>>>(x_q, W_q, x_kv, W_kvd, W_kvu, W_out,
                                           xq_bf, wq_bf, xkv_bf, wkvd_bf,
                                           wv_bf, wout_bf, wkt);

  // D1: K1+K3 fused (512 blocks) || K2 (128 blocks)
  d1_fused<<<dim3(640), 256, 0, stream>>>(xq_bf, wq_bf, xkv_bf, wkvd_bf,
                                          wkt, qlat_bf, c_kvb);

  // K4: fused gather + latent scores + softmax + latent PV, 2 queries/block
  attn_mfma<<<dim3(1024), 256, 0, stream>>>(c_kvb, qlat_bf, idx, cw_bf);

  // K5: o_bf[bq,h*64+n] = bf16(cw[bq,h,:] @ W_v[h]^T)  (BK=128, nk=1)
  gemm_nt_g4<<<dim3(1, 32, 16), 256, 0, stream>>>(
      cw_bf, 2048, 128, wv_bf, 128, 8192, nullptr, o_bf, 1024, 64, 128, 1);

  // K6: out = o @ W_out^T  (fp32 out, BK=128, nk=8)
  gemm_nt_g4<<<dim3(16, 32, 1), 256, 0, stream>>>(
      o_bf, 1024, 0, wout_bf, 1024, 0, out, nullptr, 1024, 0, 1024, 0);
}

// Round 15
// 58.863 us; speedup vs baseline: 1.0376x; 1.0261x over previous
//
#include <hip/hip_runtime.h>

// DeepSeek-MLA sparse attention, absorbed formulation, full bf16-MFMA pipeline.
// B=2 NQ=1024 NKV=2048 K=64 D=1024 H=16 LAT=128 HD=64
// Round-15: (1) REVERT round-14's attn 2-queries/block (cost +1.2 us: halved
// tail-packing granularity at unchanged occupancy). attn back to proven
// 1-query/2048-block form. (2) NEW: T1 XCD-chunked swizzle on K1 (in
// d1_fused) and K6 -- bijective remap lb=(b&7)*64+(b>>3) so each XCD's L2
// holds one contiguous A-panel + full B (2.5 MB < 4 MB), instead of 6 MB
// spill. Zero arithmetic change -> absmax canary exactly 0.0078125.
#define NKVc  2048
#define SCALE 0.125f

typedef unsigned short u16;
typedef __attribute__((ext_vector_type(8))) short short8b;     // 8 bf16 (MFMA frag)
typedef __attribute__((ext_vector_type(8))) unsigned short ushort8;
typedef __attribute__((ext_vector_type(4))) float f32x4;

__device__ __forceinline__ u16 f2bf(float f) {
  unsigned int u = __float_as_uint(f);
  return (u16)((u + 0x7FFFu + ((u >> 16) & 1u)) >> 16);   // RNE
}

#define GLOAD16(gp, lp) \
  __builtin_amdgcn_global_load_lds( \
      (const __attribute__((address_space(1))) unsigned int*)(gp), \
      (__attribute__((address_space(3))) unsigned int*)(lp), 16, 0, 0)

// ---------------------------------------------------------------------------
// Mega-conversion: all fp32->bf16 prep in ONE dispatch. Unit = 8 elements.
// ---------------------------------------------------------------------------
__device__ __forceinline__ void conv8(const float* __restrict__ in,
                                      u16* __restrict__ out, int j) {
  float4 f0 = ((const float4*)in)[j * 2];
  float4 f1 = ((const float4*)in)[j * 2 + 1];
  ushort4 a, b;
  a.x = f2bf(f0.x); a.y = f2bf(f0.y); a.z = f2bf(f0.z); a.w = f2bf(f0.w);
  b.x = f2bf(f1.x); b.y = f2bf(f1.y); b.z = f2bf(f1.z); b.w = f2bf(f1.w);
  ((ushort4*)out)[j * 2] = a;
  ((ushort4*)out)[j * 2 + 1] = b;
}

__global__ __launch_bounds__(256)
void megaconv(const float* __restrict__ xq, const float* __restrict__ wq,
              const float* __restrict__ xkv, const float* __restrict__ wkvd,
              const float* __restrict__ wkvu, const float* __restrict__ wout,
              u16* __restrict__ xq_bf, u16* __restrict__ wq_bf,
              u16* __restrict__ xkv_bf, u16* __restrict__ wkvd_bf,
              u16* __restrict__ wv_bf, u16* __restrict__ wout_bf,
              u16* __restrict__ wkt) {
  int i = blockIdx.x * 256 + threadIdx.x;
  if (i < 262144) { conv8(xq, xq_bf, i); return; }
  if (i < 393216) { conv8(wq, wq_bf, i - 262144); return; }
  if (i < 917504) { conv8(xkv, xkv_bf, i - 393216); return; }
  if (i < 933888) { conv8(wkvd, wkvd_bf, i - 917504); return; }
  if (i < 950272) { conv8(wkvu + 131072, wv_bf, i - 933888); return; }
  if (i < 1081344) { conv8(wout, wout_bf, i - 950272); return; }
  {
    int o = (i - 1081344) * 8;          // 8 consecutive hd in one (h,l)
    int hd0 = o & 63;
    int l = (o >> 6) & 127;
    int h = o >> 13;
    const float* src = wkvu + (h * 64 + hd0) * 128 + l;
    ushort8 v;
#pragma unroll
    for (int j = 0; j < 8; ++j) v[j] = f2bf(src[j * 128]);
    *(ushort8*)&wkt[o] = v;
  }
}

// ---------------------------------------------------------------------------
// GEMM-NT core (BM=64, BN=64, BK=NSUB*32, 4 waves 2x2), caller-owned LDS.
// 2-phase double buffer, full drain per step (proven structure).
// ---------------------------------------------------------------------------
template<int NSUB>
__device__ __forceinline__ void gemm_loop(
    u16* As, u16* Bs, int bm, int bn,
    const u16* __restrict__ A, int lda,
    const u16* __restrict__ B, int ldb, int K, f32x4 (&acc)[2][2]) {
  const int tid = threadIdx.x;
  const int w = tid >> 6, lane = tid & 63;
  const int wr = w >> 1, wc = w & 1;
  constexpr int BUF = NSUB * 256 * 8;

  auto stage = [&](int buf, int t) {
#pragma unroll
    for (int sub = 0; sub < NSUB; ++sub) {
      int s = w * 64 + lane;
      int row = s >> 2;
      int kc = (s & 3) ^ ((row >> 1) & 3);
      int kg = t * (NSUB * 32) + sub * 32 + kc * 8;
      GLOAD16(A + (size_t)(bm + row) * lda + kg,
              As + buf * BUF + (sub * 256 + w * 64) * 8);
      GLOAD16(B + (size_t)(bn + row) * ldb + kg,
              Bs + buf * BUF + (sub * 256 + w * 64) * 8);
    }
  };

  auto compute = [&](int buf) {
#pragma unroll
    for (int sub = 0; sub < NSUB; ++sub) {
      short8b a[2], b[2];
#pragma unroll
      for (int m = 0; m < 2; ++m) {
        int row = wr * 32 + m * 16 + (lane & 15);
        int slot = sub * 256 + row * 4 + ((lane >> 4) ^ ((row >> 1) & 3));
        a[m] = *(const short8b*)&As[buf * BUF + slot * 8];
      }
#pragma unroll
      for (int n = 0; n < 2; ++n) {
        int col = wc * 32 + n * 16 + (lane & 15);
        int slot = sub * 256 + col * 4 + ((lane >> 4) ^ ((col >> 1) & 3));
        b[n] = *(const short8b*)&Bs[buf * BUF + slot * 8];
      }
#pragma unroll
      for (int m = 0; m < 2; ++m)
#pragma unroll
        for (int n = 0; n < 2; ++n)
          acc[m][n] = __builtin_amdgcn_mfma_f32_16x16x32_bf16(a[m], b[n], acc[m][n], 0, 0, 0);
    }
  };

  stage(0, 0);
  asm volatile("s_waitcnt vmcnt(0)" ::: "memory");
  __syncthreads();
  const int nk = K / (NSUB * 32);
  for (int t = 0; t < nk; ++t) {
    int cur = t & 1;
    if (t + 1 < nk) stage(cur ^ 1, t + 1);
    compute(cur);
    asm volatile("s_waitcnt vmcnt(0)" ::: "memory");
    __syncthreads();
  }
}

__device__ __forceinline__ void gemm_epi(
    f32x4 (&acc)[2][2], int bm, int bn,
    float* __restrict__ C, u16* __restrict__ Cb, int ldc, bool obf) {
  const int lane = threadIdx.x & 63;
  const int w = threadIdx.x >> 6;
  const int wr = w >> 1, wc = w & 1;
#pragma unroll
  for (int m = 0; m < 2; ++m) {
    int row0 = bm + wr * 32 + m * 16 + (lane >> 4) * 4;
#pragma unroll
    for (int n = 0; n < 2; ++n) {
      int col = bn + wc * 32 + n * 16 + (lane & 15);
      if (obf) {
#pragma unroll
        for (int r = 0; r < 4; ++r)
          Cb[(size_t)(row0 + r) * ldc + col] = f2bf(acc[m][n][r]);
      } else {
#pragma unroll
        for (int r = 0; r < 4; ++r)
          C[(size_t)(row0 + r) * ldc + col] = acc[m][n][r];
      }
    }
  }
}

// standalone wrapper, BK=128 (K5, K6). swz: T1 XCD-chunked remap for 2D
// 512-block grids (gridDim 16x32) -- each XCD owns a contiguous by-range.
__global__ __launch_bounds__(256)
void gemm_nt_g4(const u16* __restrict__ A, int lda, long sAz,
                const u16* __restrict__ B, int ldb, long sBz,
                float* __restrict__ C, u16* __restrict__ Cb,
                int ldc, long sCz, int K, int obf, int swz) {
  int bx = blockIdx.x, by = blockIdx.y;
  if (swz) {
    int lin = blockIdx.y * 16 + blockIdx.x;     // 512 blocks, 512%8==0
    int lb = (lin & 7) * 64 + (lin >> 3);       // bijective chunk remap
    bx = lb & 15; by = lb >> 4;
  }
  __shared__ __align__(16) u16 As[2 * 1024 * 8];
  __shared__ __align__(16) u16 Bs[2 * 1024 * 8];
  f32x4 acc[2][2] = {};
  gemm_loop<4>(As, Bs, by * 64, bx * 64,
               A + (size_t)blockIdx.z * sAz, lda,
               B + (size_t)blockIdx.z * sBz, ldb, K, acc);
  gemm_epi(acc, by * 64, bx * 64,
           C ? C + (size_t)blockIdx.z * sCz : nullptr,
           Cb ? Cb + (size_t)blockIdx.z * sCz : nullptr, ldc, obf != 0);
}

// ---------------------------------------------------------------------------
// D1: [0,512)   K1+K3 fused (T1-swizzled): q-subblock in regs -> qlat directly
//     [512,640) K2: c_kvb = bf16(x_kv @ W_kvd^T), K=1024 (bf16 gload path)
// One shared 32 KB LDS allocation for both paths.
// ---------------------------------------------------------------------------
__global__ __launch_bounds__(256)
void d1_fused(const u16* __restrict__ xq_bf, const u16* __restrict__ wq_bf,
              const u16* __restrict__ xkv_bf, const u16* __restrict__ wkvd_bf,
              const u16* __restrict__ wkt, u16* __restrict__ qlat_bf,
              u16* __restrict__ c_kvb) {
  __shared__ __align__(16) u16 As[2 * 512 * 8];   // 16 KB
  __shared__ __align__(16) u16 Bs[2 * 512 * 8];   // 16 KB
  const int b = blockIdx.x;
  const int tid = threadIdx.x;
  const int w = tid >> 6, lane = tid & 63;
  const int wr = w >> 1, wc = w & 1;
  f32x4 acc[2][2] = {};

  if (b >= 512) {   // K2 path
    int b2 = b - 512;
    int bm = (b2 >> 1) * 64, bn = (b2 & 1) * 64;
    gemm_loop<2>(As, Bs, bm, bn, xkv_bf, 1024, wkvd_bf, 1024, 1024, acc);
    gemm_epi(acc, bm, bn, nullptr, c_kvb, 128, true);
    return;
  }

  // T1 XCD-chunked remap: hw id b round-robins XCDs; lb groups contiguous
  // bm per XCD -> xq panel (512KB) + wq (2MB) fit 4MB L2. Bijective (512%8==0).
  const int lb = (b & 7) * 64 + (b >> 3);
  const int h = lb & 15, bm = (lb >> 4) * 64;

  // --- K1 phase: q_sub = x_q[bm-rows] @ W_q[h-rows]^T (64x64, head h) ---
  gemm_loop<2>(As, Bs, bm, h * 64, xq_bf, 1024, wq_bf, 1024, 1024, acc);
  // loop ended with full drain + barrier -> As/Bs free for reuse.

  // --- K3 phase: qlat[bm-rows][h][l] = q_sub @ wkt[h]^T  (M=64,N=128,K=64) --
#pragma unroll
  for (int i = 0; i < 4; ++i) {
    int s = (w * 4 + i) * 64 + lane;      // 0..1023
    int l = s >> 3, c = s & 7;
    GLOAD16(wkt + h * 8192 + l * 64 + ((c ^ (l & 7)) * 8), Bs + s * 8);
  }
#pragma unroll
  for (int mm = 0; mm < 2; ++mm)
#pragma unroll
    for (int nn = 0; nn < 2; ++nn) {
      int hd = wc * 32 + nn * 16 + (lane & 15);
      int c = hd >> 3;
#pragma unroll
      for (int rr = 0; rr < 4; ++rr) {
        int row = wr * 32 + mm * 16 + (lane >> 4) * 4 + rr;
        As[row * 64 + ((c ^ (row & 7)) * 8) + (hd & 7)] = f2bf(acc[mm][nn][rr]);
      }
    }
  asm volatile("s_waitcnt vmcnt(0)" ::: "memory");
  __syncthreads();

  f32x4 acc2[2][4] = {};
#pragma unroll
  for (int ks = 0; ks < 2; ++ks) {
    short8b af[2], bv[4];
#pragma unroll
    for (int mm = 0; mm < 2; ++mm) {
      int row = wr * 32 + mm * 16 + (lane & 15);
      int ch = ks * 4 + (lane >> 4);
      af[mm] = *(const short8b*)&As[row * 64 + ((ch ^ (row & 7)) * 8)];
    }
#pragma unroll
    for (int nf = 0; nf < 4; ++nf) {
      int l = wc * 64 + nf * 16 + (lane & 15);
      int ch = ks * 4 + (lane >> 4);
      bv[nf] = *(const short8b*)&Bs[(l * 8 + (ch ^ (l & 7))) * 8];
    }
#pragma unroll
    for (int mm = 0; mm < 2; ++mm)
#pragma unroll
      for (int nf = 0; nf < 4; ++nf)
        acc2[mm][nf] = __builtin_amdgcn_mfma_f32_16x16x32_bf16(af[mm], bv[nf], acc2[mm][nf], 0, 0, 0);
  }
#pragma unroll
  for (int mm = 0; mm < 2; ++mm) {
    int row0 = bm + wr * 32 + mm * 16 + (lane >> 4) * 4;
#pragma unroll
    for (int nf = 0; nf < 4; ++nf) {
      int l = wc * 64 + nf * 16 + (lane & 15);
#pragma unroll
      for (int r = 0; r < 4; ++r)
        qlat_bf[(size_t)(row0 + r) * 2048 + h * 128 + l] = f2bf(acc2[mm][nf][r]);
    }
  }
}

// ---------------------------------------------------------------------------
// Fused sparse attention in latent space, bf16 MFMA. One block per (b,q).
// (round-11 proven form, reverted from the 2-query merge)
// ---------------------------------------------------------------------------
__global__ __launch_bounds__(256)
void attn_mfma(const u16* __restrict__ c_kvb,   // (B, 2048, 128) bf16
               const u16* __restrict__ q_latb,  // (BQ, 16, 128) bf16
               const int* __restrict__ indices, // (BQ, 64)
               u16* __restrict__ cw_bf) {       // (BQ, 16, 128) bf16
  __shared__ __align__(16) u16 qls[256 * 8];
  __shared__ __align__(16) u16 csa[1024 * 8];
  __shared__ __align__(16) u16 cst[128 * 72];
  __shared__ __align__(16) u16 pT[16 * 72];
  __shared__ __align__(16) float redmax[64];
  __shared__ __align__(16) float redsum[64];
  __shared__ __align__(16) u16 outst[2048];

  const int tid = threadIdx.x;
  const int w = tid >> 6, lane = tid & 63;
  const int bq = blockIdx.x;
  const int b = bq >> 10;

  {
    int h = tid >> 4, c = tid & 15;
    ushort8 v = *(const ushort8*)(q_latb + (size_t)bq * 2048 + tid * 8);
    *(ushort8*)&qls[(h * 16 + (c ^ h)) * 8] = v;
  }
  {
    int kidx = indices[bq * 64 + lane];
    const u16* src = c_kvb + ((size_t)b * NKVc + kidx) * 128 + w * 32;
    ushort8 v[4];
#pragma unroll
    for (int t = 0; t < 4; ++t) v[t] = *(const ushort8*)(src + t * 8);
#pragma unroll
    for (int t = 0; t < 4; ++t) {
      int c = w * 4 + t;
      *(ushort8*)&csa[(lane * 16 + (c ^ (lane & 15))) * 8] = v[t];
    }
#pragma unroll
    for (int t = 0; t < 4; ++t)
#pragma unroll
      for (int j = 0; j < 8; ++j)
        cst[(w * 32 + t * 8 + j) * 72 + lane] = v[t][j];
  }
  __syncthreads();

  f32x4 sacc = {};
#pragma unroll
  for (int kc = 0; kc < 4; ++kc) {
    int ar = w * 16 + (lane & 15);
    int ac = kc * 4 + (lane >> 4);
    short8b av = *(const short8b*)&csa[(ar * 16 + (ac ^ (ar & 15))) * 8];
    int bh = lane & 15;
    short8b bv = *(const short8b*)&qls[(bh * 16 + (ac ^ bh)) * 8];
    sacc = __builtin_amdgcn_mfma_f32_16x16x32_bf16(av, bv, sacc, 0, 0, 0);
  }
  float s0 = sacc[0] * SCALE, s1 = sacc[1] * SCALE;
  float s2 = sacc[2] * SCALE, s3 = sacc[3] * SCALE;
  float mx = fmaxf(fmaxf(s0, s1), fmaxf(s2, s3));
  mx = fmaxf(mx, __shfl_xor(mx, 16));
  mx = fmaxf(mx, __shfl_xor(mx, 32));
  if (lane < 16) redmax[w * 16 + lane] = mx;
  __syncthreads();
  const int h = lane & 15;
  float m4 = fmaxf(fmaxf(redmax[h], redmax[16 + h]),
                   fmaxf(redmax[32 + h], redmax[48 + h]));
  float p0 = __expf(s0 - m4), p1 = __expf(s1 - m4);
  float p2 = __expf(s2 - m4), p3 = __expf(s3 - m4);
  float sm = p0 + p1 + p2 + p3;
  sm += __shfl_xor(sm, 16);
  sm += __shfl_xor(sm, 32);
  if (lane < 16) redsum[w * 16 + lane] = sm;
  __syncthreads();
  float tot = redsum[h] + redsum[16 + h] + redsum[32 + h] + redsum[48 + h];
  float inv = 1.0f / tot;
  {
    ushort4 pw;
    pw.x = f2bf(p0 * inv); pw.y = f2bf(p1 * inv);
    pw.z = f2bf(p2 * inv); pw.w = f2bf(p3 * inv);
    *(ushort4*)&pT[h * 72 + w * 16 + (lane >> 4) * 4] = pw;
  }
  __syncthreads();

  f32x4 pacc0 = {}, pacc1 = {};
#pragma unroll
  for (int kc = 0; kc < 2; ++kc) {
    short8b pa = *(const short8b*)&pT[(lane & 15) * 72 + kc * 32 + (lane >> 4) * 8];
    int cch = kc * 4 + (lane >> 4);
    int n0 = w * 32 + (lane & 15);
    short8b b0 = *(const short8b*)&cst[n0 * 72 + cch * 8];
    short8b b1 = *(const short8b*)&cst[(n0 + 16) * 72 + cch * 8];
    pacc0 = __builtin_amdgcn_mfma_f32_16x16x32_bf16(pa, b0, pacc0, 0, 0, 0);
    pacc1 = __builtin_amdgcn_mfma_f32_16x16x32_bf16(pa, b1, pacc1, 0, 0, 0);
  }
#pragma unroll
  for (int r = 0; r < 4; ++r) {
    int hh = (lane >> 4) * 4 + r;
    outst[hh * 128 + w * 32 + (lane & 15)] = f2bf(pacc0[r]);
    outst[hh * 128 + w * 32 + 16 + (lane & 15)] = f2bf(pacc1[r]);
  }
  __syncthreads();
  *(ushort8*)(cw_bf + (size_t)bq * 2048 + tid * 8) = *(const ushort8*)&outst[tid * 8];
}

extern "C" void kernel_launch(void* const* d_in, const int* in_sizes, int n_in,
                              void* d_out, int out_size, void* d_ws, size_t ws_size,
                              hipStream_t stream) {
  const float* x_q    = (const float*)d_in[0];
  const float* x_kv   = (const float*)d_in[1];
  const int*   idx    = (const int*)  d_in[2];
  const float* W_q    = (const float*)d_in[3];
  const float* W_kvd  = (const float*)d_in[4];
  const float* W_kvu  = (const float*)d_in[5];
  const float* W_out  = (const float*)d_in[6];
  float* out = (float*)d_out;

  // byte-offset workspace carve; top = 42 MB (proven footprint)
  char* wsb = (char*)d_ws;
  u16* xq_bf   = (u16*)(wsb + 0);                            // 4 MB
  u16* wq_bf   = (u16*)(wsb + (4u << 20));                   // 2 MB
  u16* xkv_bf  = (u16*)(wsb + (6u << 20));                   // 8 MB
  u16* wkvd_bf = (u16*)(wsb + (14u << 20));                  // 256 KB
  u16* wkt     = (u16*)(wsb + (14u << 20) + (256u << 10));   // 256 KB
  u16* wv_bf   = (u16*)(wsb + (14u << 20) + (512u << 10));   // 256 KB
  u16* wout_bf = (u16*)(wsb + (14u << 20) + (768u << 10));   // 2 MB
  u16* c_kvb   = (u16*)(wsb + (21u << 20));                  // 1 MB
  u16* qlat_bf = (u16*)(wsb + (22u << 20));                  // 8 MB
  u16* cw_bf   = (u16*)(wsb + (30u << 20));                  // 8 MB
  u16* o_bf    = (u16*)(wsb + (38u << 20));                  // 4 MB

  // C0: all conversions in one dispatch
  megaconv<<<dim3(4288), 256, 0, stream>>>(x_q, W_q, x_kv, W_kvd, W_kvu, W_out,
                                           xq_bf, wq_bf, xkv_bf, wkvd_bf,
                                           wv_bf, wout_bf, wkt);

  // D1: K1+K3 fused, T1-swizzled (512 blocks) || K2 (128 blocks)
  d1_fused<<<dim3(640), 256, 0, stream>>>(xq_bf, wq_bf, xkv_bf, wkvd_bf,
                                          wkt, qlat_bf, c_kvb);

  // K4: fused gather + latent scores + softmax + latent PV (1 query/block)
  attn_mfma<<<dim3(2048), 256, 0, stream>>>(c_kvb, qlat_bf, idx, cw_bf);

  // K5: o_bf[bq,h*64+n] = bf16(cw[bq,h,:] @ W_v[h]^T)  (BK=128, nk=1, no swz)
  gemm_nt_g4<<<dim3(1, 32, 16), 256, 0, stream>>>(
      cw_bf, 2048, 128, wv_bf, 128, 8192, nullptr, o_bf, 1024, 64, 128, 1, 0);

  // K6: out = o @ W_out^T  (fp32 out, BK=128, nk=8, T1-swizzled)
  gemm_nt_g4<<<dim3(16, 32, 1), 256, 0, stream>>>(
      o_bf, 1024, 0, wout_bf, 1024, 0, out, nullptr, 1024, 0, 1024, 0, 1);
}